// Round 4
// baseline (936.222 us; speedup 1.0000x reference)
//
#include <hip/hip_runtime.h>
#include <hip/hip_bf16.h>

// LSTM  B=256, S=512, I=512, H=128, OUT=2
// R4: latency-hide the serial recurrence via TWO independent recurrences per
//     consumer block (batch groups A/B, 4 rows each). The consumer substep is
//     a single dependency chain (~1690 cyc) with nothing to overlap; pairing
//     two chains in one wave lets ds_read/MFMA/transpose/EW latencies of A
//     hide under B. Consumer blocks 64->32 (8 batch rows each); producers
//     192->224 (span shrinks ~14%). Wh fragments shared between groups.
// R3 retained: coherence-neutral handshake (RELAXED wave-0 spin; xg crosses
//     XCDs via RELAXED/AGENT 8B atomics = write-through / L2-bypass).
// R0 retained: sched_barrier(0) pins gl_lds/prefetch issue order, fences raw
//     s_barrier and same-wave-LDS waits.

typedef __attribute__((ext_vector_type(8))) short short8;      // 8 bf16
typedef __attribute__((ext_vector_type(4))) float floatx4;
typedef __attribute__((ext_vector_type(4))) unsigned short ushortx4;
typedef __attribute__((ext_vector_type(2))) unsigned int uint2v;

#define LOG2E 1.44269504088896340736f
#define NPROD 224

__device__ __forceinline__ unsigned short f2bf(float f) {
  unsigned int u = __builtin_bit_cast(unsigned int, f);
  u = (u + 0x7fffu + ((u >> 16) & 1u)) >> 16;   // RNE
  return (unsigned short)u;
}
__device__ __forceinline__ float bf2f(unsigned short u) {
  unsigned int v = ((unsigned int)u) << 16;
  return __builtin_bit_cast(float, v);
}
__device__ __forceinline__ float sigf(float x) {
  return __builtin_amdgcn_rcpf(1.0f + __builtin_amdgcn_exp2f(-LOG2E * x));
}
__device__ __forceinline__ float tanhf_(float x) {
  return 1.0f - 2.0f * __builtin_amdgcn_rcpf(1.0f + __builtin_amdgcn_exp2f(2.0f * LOG2E * x));
}
__device__ __forceinline__ void bar_lds() {
  asm volatile("s_waitcnt lgkmcnt(0)" ::: "memory");
  __builtin_amdgcn_s_barrier();
  __builtin_amdgcn_sched_barrier(0);
}
__device__ __forceinline__ void gl_lds16(const void* g, void* l) {
  __builtin_amdgcn_global_load_lds(
      (const __attribute__((address_space(1))) unsigned int*)g,
      (__attribute__((address_space(3))) unsigned int*)l, 16, 0, 0);
}

// ---------------- K1: pack Wi / Wh into B-fragment order (bf16) ---------------
__global__ void pack_kernel(const float* __restrict__ Wi, const float* __restrict__ Wh,
                            unsigned short* __restrict__ Wi_p, unsigned short* __restrict__ Wh_p,
                            unsigned int* __restrict__ flags) {
  if (blockIdx.x == 0 && threadIdx.x < 8) flags[threadIdx.x] = 0u;
  int idx = blockIdx.x * 256 + threadIdx.x;
  if (idx < 262144) {
    int j = idx & 7, lane = (idx >> 3) & 63, nt = (idx >> 9) & 31, kk = idx >> 14;
    int k = kk * 32 + ((lane >> 4) * 8) + j;
    int n = nt * 16 + (lane & 15);
    Wi_p[idx] = f2bf(Wi[k * 512 + n]);
  } else {
    int i2 = idx - 262144;
    int j = i2 & 7, lane = (i2 >> 3) & 63, nt = (i2 >> 9) & 31, kk = i2 >> 14;
    int k = kk * 32 + ((lane >> 4) * 8) + j;
    int n = nt * 16 + (lane & 15);
    Wh_p[i2] = f2bf(Wh[k * 512 + n]);
  }
}

// ---------------- fused: producer GEMM (bids 0..223) + consumer LSTM (224..255)
__global__ __launch_bounds__(512, 2) void fused_kernel(
    const float* __restrict__ x, const unsigned short* __restrict__ Wi_p,
    const float* __restrict__ bias, unsigned int* __restrict__ xg5,
    const unsigned short* __restrict__ Wh_p, const float* __restrict__ Wd,
    const float* __restrict__ bd, float* __restrict__ out,
    unsigned int* __restrict__ flags) {
  __shared__ __align__(16) unsigned short As[128 * 72];        // 18.4 KB (producer)
  __shared__ __align__(16) unsigned short Bs[2 * 32 * 64 * 8]; // 64 KB   (producer)
  __shared__ __align__(16) unsigned short hb[4 * 2240];        // 17.9 KB (consumer: 2 grp x 2 buf)
  __shared__ __align__(16) float gbw[8 * 640];                 // 20 KB   (consumer: 2 grp)

  const int tid = threadIdx.x;
  const int lane = tid & 63;
  const int w = tid >> 6;          // 0..7
  const int quad = lane >> 4;
  const int lm = lane & 15;

  if (blockIdx.x < NPROD) {
    // =========================== PRODUCER ====================================
    const int wm = w >> 2, wn = w & 3;

    float bs_[4][2];
    #pragma unroll
    for (int g = 0; g < 4; ++g)
      #pragma unroll
      for (int jc = 0; jc < 2; ++jc)
        bs_[g][jc] = bias[g * 128 + wn * 32 + jc * 16 + lm];

    for (int t = blockIdx.x; t < 1024; t += NPROD) {
      const int s = t >> 1;
      const int b0 = (t & 1) * 128;

      floatx4 acc[4][8];
      #pragma unroll
      for (int a = 0; a < 4; ++a)
        #pragma unroll
        for (int b2 = 0; b2 < 8; ++b2) { acc[a][b2].x = 0.f; acc[a][b2].y = 0.f; acc[a][b2].z = 0.f; acc[a][b2].w = 0.f; }

      // A rows r = w*16 + i*4 + quad (i 0..3), col lm*4; batch stride 262144 floats.
      const float* xbase = x + ((size_t)(b0 + w * 16 + quad) * 512 + s) * 512 + lm * 4;

      floatx4 cur[4], nxt[4];
      #pragma unroll
      for (int i = 0; i < 4; ++i)
        cur[i] = *(const floatx4*)(xbase + (size_t)i * 1048576);

      for (int kt = 0; kt < 8; ++kt) {
        bar_lds();   // prior compute's LDS reads done; vmcnt NOT drained
        // stage A tile from registers (compiler waits cur's vmcnt here)
        #pragma unroll
        for (int i = 0; i < 4; ++i) {
          int r = w * 16 + i * 4 + quad;
          ushortx4 u;
          u.x = f2bf(cur[i].x); u.y = f2bf(cur[i].y); u.z = f2bf(cur[i].z); u.w = f2bf(cur[i].w);
          *(ushortx4*)(&As[r * 72 + lm * 4]) = u;
        }
        // stage B tile (64 KB) async global->LDS: 8 gl_lds per thread
        #pragma unroll
        for (int c = 0; c < 8; ++c) {
          int kg = c & 1, ntl = (c >> 1) * 8 + w;
          const unsigned short* src = Wi_p + ((size_t)((kt * 2 + kg) * 32 + ntl) * 64 + lane) * 8;
          unsigned short* dst = &Bs[(size_t)((kg * 32 + ntl) * 64) * 8];
          gl_lds16(src, dst);
        }
        // vmcnt(4) below assumes the 8 gl_lds were ISSUED before the 4 A loads.
        __builtin_amdgcn_sched_barrier(0);
        if (kt < 7) {
          #pragma unroll
          for (int i = 0; i < 4; ++i)
            nxt[i] = *(const floatx4*)(xbase + (size_t)i * 1048576 + (kt + 1) * 64);
          asm volatile("s_waitcnt vmcnt(4) lgkmcnt(0)" ::: "memory");
        } else {
          asm volatile("s_waitcnt vmcnt(0) lgkmcnt(0)" ::: "memory");
        }
        __builtin_amdgcn_s_barrier();
        __builtin_amdgcn_sched_barrier(0);   // no ds_read may hoist above barrier
        #pragma unroll
        for (int ks = 0; ks < 2; ++ks) {
          short8 af[4];
          #pragma unroll
          for (int mt = 0; mt < 4; ++mt) {
            int m = wm * 64 + mt * 16 + lm;
            af[mt] = *(const short8*)(&As[m * 72 + ks * 32 + quad * 8]);
          }
          #pragma unroll
          for (int nt = 0; nt < 8; ++nt) {
            int g = nt >> 1, jc = nt & 1;
            int ntl = g * 8 + wn * 2 + jc;
            short8 bfv = *(const short8*)(&Bs[(size_t)((ks * 32 + ntl) * 64 + lane) * 8]);
            #pragma unroll
            for (int mt = 0; mt < 4; ++mt)
              acc[mt][nt] = __builtin_amdgcn_mfma_f32_16x16x32_bf16(af[mt], bfv, acc[mt][nt], 0, 0, 0);
          }
        }
        #pragma unroll
        for (int i = 0; i < 4; ++i) cur[i] = nxt[i];
      }
      // epilogue: per-cell 4-gate 8B RELAXED/AGENT atomic stores (write-through;
      // L2 never holds dirty xg lines).
      #pragma unroll
      for (int mt = 0; mt < 4; ++mt) {
        int bbase = b0 + wm * 64 + mt * 16 + quad * 4;
        #pragma unroll
        for (int jc = 0; jc < 2; ++jc) {
          int wv = wn * 2 + jc;
          #pragma unroll
          for (int rr = 0; rr < 4; ++rr) {
            size_t cell = ((size_t)s * 64 + ((bbase + rr) >> 2)) * 512 + wv * 64 + rr * 16 + lm;
            float g0 = acc[mt][0 + jc][rr] + bs_[0][jc];
            float g1 = acc[mt][2 + jc][rr] + bs_[1][jc];
            float g2 = acc[mt][4 + jc][rr] + bs_[2][jc];
            float g3 = acc[mt][6 + jc][rr] + bs_[3][jc];
            unsigned long long v64 =
                (unsigned long long)((unsigned int)f2bf(g0) | ((unsigned int)f2bf(g1) << 16)) |
                ((unsigned long long)((unsigned int)f2bf(g2) | ((unsigned int)f2bf(g3) << 16)) << 32);
            __hip_atomic_store((unsigned long long*)xg5 + cell, v64,
                               __ATOMIC_RELAXED, __HIP_MEMORY_SCOPE_AGENT);
          }
        }
      }
      // publish: __syncthreads drains every thread's vmcnt (stores acked at the
      // coherence point); one release add per tile.
      __syncthreads();
      __builtin_amdgcn_sched_barrier(0);
      if (tid == 0)
        __hip_atomic_fetch_add(&flags[t >> 7], 1u, __ATOMIC_RELEASE, __HIP_MEMORY_SCOPE_AGENT);
    }
  } else {
    // =========================== CONSUMER ====================================
    // block bb (0..31) owns batch rows 8bb..8bb+7 = groups A (bgrp 2bb) and
    // B (bgrp 2bb+1). Two independent recurrences interleaved in each wave.
    const int bb = blockIdx.x - NPROD;

    for (int i = tid; i < 4 * 2240; i += 512) hb[i] = 0;

    // Wh B-fragments: gate g -> ntg = g*8 + w (cols g*128 + w*16 + lm); shared
    // by both groups.
    short8 bfr[4][4];
    #pragma unroll
    for (int kk = 0; kk < 4; ++kk)
      #pragma unroll
      for (int g = 0; g < 4; ++g)
        bfr[kk][g] = *(const short8*)(Wh_p + ((size_t)(kk * 32 + g * 8 + w) * 64 + lane) * 8);

    float cstA = 0.f, cstB = 0.f;   // cell states for (row quad, col w*16+lm)

    // xg: cell index within bgrp = tid; per-s stride = 64*512 cells = 32768 u64
    const unsigned long long* xpA = (const unsigned long long*)xg5 + ((size_t)(2 * bb) * 512 + tid);
    const unsigned long long* xpB = (const unsigned long long*)xg5 + ((size_t)(2 * bb + 1) * 512 + tid);
    float* gwA = gbw + w * 640;
    float* gwB = gbw + w * 640 + 320;

    auto at_load8 = [](const unsigned long long* p) -> uint2v {
      unsigned long long v = __hip_atomic_load(p, __ATOMIC_RELAXED, __HIP_MEMORY_SCOPE_AGENT);
      uint2v r; r.x = (unsigned int)v; r.y = (unsigned int)(v >> 32); return r;
    };

    __syncthreads();   // hb zeros visible

    uint2v xgaA, xgbA, xgaB, xgbB;

    auto substep = [&](const int rp, uint2v& xcA, uint2v& xcB, int spre) {
      uint2v xvA = xcA, xvB = xcB;
      if (spre < 512) {
        xcA = at_load8(xpA + (size_t)spre * 32768);   // in flight across bar_lds
        xcB = at_load8(xpB + (size_t)spre * 32768);
      }

      // A-frags both groups: 16x ds_read_b64 (rows 4-15 read zeros)
      short8 afA[4], afB[4];
      #pragma unroll
      for (int kk = 0; kk < 4; ++kk) {
        const unsigned short* pA = &hb[rp * 2240 + lm * 140 + kk * 32 + quad * 8];
        union { short8 v; ushortx4 h[2]; } tA, tB;
        tA.h[0] = *(const ushortx4*)(pA);
        tA.h[1] = *(const ushortx4*)(pA + 4);
        tB.h[0] = *(const ushortx4*)(pA + 4480);
        tB.h[1] = *(const ushortx4*)(pA + 4484);
        afA[kk] = tA.v; afB[kk] = tB.v;
      }

      floatx4 accA[4], accB[4];
      #pragma unroll
      for (int g = 0; g < 4; ++g) {
        accA[g].x = 0.f; accA[g].y = 0.f; accA[g].z = 0.f; accA[g].w = 0.f;
        accB[g].x = 0.f; accB[g].y = 0.f; accB[g].z = 0.f; accB[g].w = 0.f;
      }
      #pragma unroll
      for (int kk = 0; kk < 4; ++kk)
        #pragma unroll
        for (int g = 0; g < 4; ++g)
          accA[g] = __builtin_amdgcn_mfma_f32_16x16x32_bf16(afA[kk], bfr[kk][g], accA[g], 0, 0, 0);
      // transpose A issued while B's MFMAs run
      if (lane < 16) {
        #pragma unroll
        for (int r = 0; r < 4; ++r) {
          floatx4 t4;
          t4.x = accA[0][r]; t4.y = accA[1][r]; t4.z = accA[2][r]; t4.w = accA[3][r];
          *(floatx4*)(gwA + lm * 20 + r * 4) = t4;
        }
      }
      #pragma unroll
      for (int kk = 0; kk < 4; ++kk)
        #pragma unroll
        for (int g = 0; g < 4; ++g)
          accB[g] = __builtin_amdgcn_mfma_f32_16x16x32_bf16(afB[kk], bfr[kk][g], accB[g], 0, 0, 0);
      if (lane < 16) {
        #pragma unroll
        for (int r = 0; r < 4; ++r) {
          floatx4 t4;
          t4.x = accB[0][r]; t4.y = accB[1][r]; t4.z = accB[2][r]; t4.w = accB[3][r];
          *(floatx4*)(gwB + lm * 20 + r * 4) = t4;
        }
      }
      asm volatile("s_waitcnt lgkmcnt(0)" ::: "memory");   // same-wave DS order
      __builtin_amdgcn_sched_barrier(0);                   // rule-18 fence
      floatx4 gvA = *(const floatx4*)(gwA + lm * 20 + quad * 4);
      floatx4 gvB = *(const floatx4*)(gwB + lm * 20 + quad * 4);

      // EW group A
      {
        float pre0 = gvA.x + bf2f((unsigned short)(xvA.x & 0xffffu));
        float pre1 = gvA.y + bf2f((unsigned short)(xvA.x >> 16));
        float pre2 = gvA.z + bf2f((unsigned short)(xvA.y & 0xffffu));
        float pre3 = gvA.w + bf2f((unsigned short)(xvA.y >> 16));
        float cc = sigf(pre1) * cstA + sigf(pre0) * tanhf_(pre2);
        cstA = cc;
        float hv = sigf(pre3) * tanhf_(cc);
        hb[(rp ^ 1) * 2240 + quad * 140 + w * 16 + lm] = f2bf(hv);
      }
      // EW group B
      {
        float pre0 = gvB.x + bf2f((unsigned short)(xvB.x & 0xffffu));
        float pre1 = gvB.y + bf2f((unsigned short)(xvB.x >> 16));
        float pre2 = gvB.z + bf2f((unsigned short)(xvB.y & 0xffffu));
        float pre3 = gvB.w + bf2f((unsigned short)(xvB.y >> 16));
        float cc = sigf(pre1) * cstB + sigf(pre0) * tanhf_(pre2);
        cstB = cc;
        float hv = sigf(pre3) * tanhf_(cc);
        hb[4480 + (rp ^ 1) * 2240 + quad * 140 + w * 16 + lm] = f2bf(hv);
      }
      bar_lds();   // h(s+1) visible to all; vmcnt NOT drained
    };

    for (int c = 0; c < 8; ++c) {
      // wave 0 polls with RELAXED loads (no cache-invalidate side effects).
      if (w == 0) {
        while (__hip_atomic_load(&flags[c], __ATOMIC_RELAXED, __HIP_MEMORY_SCOPE_AGENT) < 128u)
          __builtin_amdgcn_s_sleep(2);
      }
      bar_lds();
      // fresh (re)load of the first two steps of this chunk -- overwrites any
      // tail prefetch that crossed an unpublished boundary.
      xgaA = at_load8(xpA + (size_t)(c * 64) * 32768);
      xgbA = at_load8(xpA + (size_t)(c * 64 + 1) * 32768);
      xgaB = at_load8(xpB + (size_t)(c * 64) * 32768);
      xgbB = at_load8(xpB + (size_t)(c * 64 + 1) * 32768);
      #pragma unroll 1
      for (int s2 = 0; s2 < 64; s2 += 2) {
        int s = c * 64 + s2;
        substep(0, xgaA, xgaB, s + 2);
        substep(1, xgbA, xgbB, s + 3);
      }
    }

    // head: h_last in buf 0 of each group (s=511 writes buf 0)
    if (tid < 16) {
      int rw = tid >> 1, co = tid & 1;   // rw 0..7
      const unsigned short* hrow = (rw < 4) ? &hb[rw * 140] : &hb[4480 + (rw - 4) * 140];
      float a = bd[co];
      for (int j2 = 0; j2 < 128; ++j2)
        a += bf2f(hrow[j2]) * Wd[j2 * 2 + co];
      out[(bb * 8 + rw) * 2 + co] = a;
    }
  }
}

extern "C" void kernel_launch(void* const* d_in, const int* in_sizes, int n_in,
                              void* d_out, int out_size, void* d_ws, size_t ws_size,
                              hipStream_t stream) {
  const float* x  = (const float*)d_in[0];
  const float* Wi = (const float*)d_in[1];
  const float* Wh = (const float*)d_in[2];
  const float* b  = (const float*)d_in[3];
  const float* Wd = (const float*)d_in[4];
  const float* bd = (const float*)d_in[5];
  float* out = (float*)d_out;

  unsigned short* Wi_p = (unsigned short*)d_ws;            // 512 KB
  unsigned short* Wh_p = Wi_p + 262144;                    // 128 KB
  unsigned int*   flags = (unsigned int*)(Wh_p + 65536);   // 512 B (8 used)
  unsigned int*   xg5  = flags + 128;                      // 134.2 MB

  pack_kernel<<<1280, 256, 0, stream>>>(Wi, Wh, Wi_p, Wh_p, flags);
  fused_kernel<<<256, 512, 0, stream>>>(x, Wi_p, b, xg5, Wh_p, Wd, bd, out, flags);
}

// Round 6
// 664.874 us; speedup vs baseline: 1.4081x; 1.4081x over previous
//
#include <hip/hip_runtime.h>
#include <hip/hip_bf16.h>

// LSTM  B=256, S=512, I=512, H=128, OUT=2
// R6: R5's ds_bpermute redistribution REVERTED (failed refcheck; dataflow was
//     paper-identical to the verified transpose -> primitive behavior not
//     predictable -> don't ship). Base = R3 (433us fused, verified).
//     Low-risk trims only:
//       - hb stride 140 -> 152 shorts (304B = 16B-multiple): af fragment loads
//         become single ds_read_b128 (4 instrs/wave instead of 8), bank
//         aliasing (lm*12+quad*4)%32 ~2-way (free).
//       - af ds_reads issue BEFORE the xg global prefetch in the substep
//         (af heads the dependency chain; start its LDS latency earlier).
// R3 retained: coherence-neutral handshake (RELAXED wave-0 spin; xg crosses
//     XCDs via RELAXED/AGENT 8B atomics = write-through / L2-bypass).
// R0 retained: sched_barrier(0) pins gl_lds/prefetch issue order, fences raw
//     s_barrier and same-wave-LDS waits.

typedef __attribute__((ext_vector_type(8))) short short8;      // 8 bf16
typedef __attribute__((ext_vector_type(4))) float floatx4;
typedef __attribute__((ext_vector_type(4))) unsigned short ushortx4;
typedef __attribute__((ext_vector_type(2))) unsigned int uint2v;

#define LOG2E 1.44269504088896340736f
#define NPROD 192
#define HBS 152              // hb row stride (shorts); 304B = 16B-multiple
#define HBUF (16 * HBS)      // one hb buffer (shorts)

__device__ __forceinline__ unsigned short f2bf(float f) {
  unsigned int u = __builtin_bit_cast(unsigned int, f);
  u = (u + 0x7fffu + ((u >> 16) & 1u)) >> 16;   // RNE
  return (unsigned short)u;
}
__device__ __forceinline__ float bf2f(unsigned short u) {
  unsigned int v = ((unsigned int)u) << 16;
  return __builtin_bit_cast(float, v);
}
__device__ __forceinline__ float sigf(float x) {
  return __builtin_amdgcn_rcpf(1.0f + __builtin_amdgcn_exp2f(-LOG2E * x));
}
__device__ __forceinline__ float tanhf_(float x) {
  return 1.0f - 2.0f * __builtin_amdgcn_rcpf(1.0f + __builtin_amdgcn_exp2f(2.0f * LOG2E * x));
}
__device__ __forceinline__ void bar_lds() {
  asm volatile("s_waitcnt lgkmcnt(0)" ::: "memory");
  __builtin_amdgcn_s_barrier();
  __builtin_amdgcn_sched_barrier(0);
}
__device__ __forceinline__ void gl_lds16(const void* g, void* l) {
  __builtin_amdgcn_global_load_lds(
      (const __attribute__((address_space(1))) unsigned int*)g,
      (__attribute__((address_space(3))) unsigned int*)l, 16, 0, 0);
}

// ---------------- K1: pack Wi / Wh into B-fragment order (bf16) ---------------
__global__ void pack_kernel(const float* __restrict__ Wi, const float* __restrict__ Wh,
                            unsigned short* __restrict__ Wi_p, unsigned short* __restrict__ Wh_p,
                            unsigned int* __restrict__ flags) {
  if (blockIdx.x == 0 && threadIdx.x < 8) flags[threadIdx.x] = 0u;
  int idx = blockIdx.x * 256 + threadIdx.x;
  if (idx < 262144) {
    int j = idx & 7, lane = (idx >> 3) & 63, nt = (idx >> 9) & 31, kk = idx >> 14;
    int k = kk * 32 + ((lane >> 4) * 8) + j;
    int n = nt * 16 + (lane & 15);
    Wi_p[idx] = f2bf(Wi[k * 512 + n]);
  } else {
    int i2 = idx - 262144;
    int j = i2 & 7, lane = (i2 >> 3) & 63, nt = (i2 >> 9) & 31, kk = i2 >> 14;
    int k = kk * 32 + ((lane >> 4) * 8) + j;
    int n = nt * 16 + (lane & 15);
    Wh_p[i2] = f2bf(Wh[k * 512 + n]);
  }
}

// ---------------- fused: producer GEMM (bids 0..191) + consumer LSTM (192..255)
__global__ __launch_bounds__(512, 2) void fused_kernel(
    const float* __restrict__ x, const unsigned short* __restrict__ Wi_p,
    const float* __restrict__ bias, unsigned int* __restrict__ xg5,
    const unsigned short* __restrict__ Wh_p, const float* __restrict__ Wd,
    const float* __restrict__ bd, float* __restrict__ out,
    unsigned int* __restrict__ flags) {
  __shared__ __align__(16) unsigned short As[128 * 72];        // 18.4 KB (producer)
  __shared__ __align__(16) unsigned short Bs[2 * 32 * 64 * 8]; // 64 KB   (producer)
  __shared__ __align__(16) unsigned short hb[2 * HBUF];        // 9.5 KB  (consumer)
  __shared__ __align__(16) float gbw[8 * 320];                 // 10 KB   (consumer)

  const int tid = threadIdx.x;
  const int lane = tid & 63;
  const int w = tid >> 6;          // 0..7
  const int quad = lane >> 4;
  const int lm = lane & 15;

  if (blockIdx.x < NPROD) {
    // =========================== PRODUCER ====================================
    const int wm = w >> 2, wn = w & 3;

    float bs_[4][2];
    #pragma unroll
    for (int g = 0; g < 4; ++g)
      #pragma unroll
      for (int jc = 0; jc < 2; ++jc)
        bs_[g][jc] = bias[g * 128 + wn * 32 + jc * 16 + lm];

    for (int t = blockIdx.x; t < 1024; t += NPROD) {
      const int s = t >> 1;
      const int b0 = (t & 1) * 128;

      floatx4 acc[4][8];
      #pragma unroll
      for (int a = 0; a < 4; ++a)
        #pragma unroll
        for (int b2 = 0; b2 < 8; ++b2) { acc[a][b2].x = 0.f; acc[a][b2].y = 0.f; acc[a][b2].z = 0.f; acc[a][b2].w = 0.f; }

      // A rows r = w*16 + i*4 + quad (i 0..3), col lm*4; batch stride 262144 floats.
      const float* xbase = x + ((size_t)(b0 + w * 16 + quad) * 512 + s) * 512 + lm * 4;

      floatx4 cur[4], nxt[4];
      #pragma unroll
      for (int i = 0; i < 4; ++i)
        cur[i] = *(const floatx4*)(xbase + (size_t)i * 1048576);

      for (int kt = 0; kt < 8; ++kt) {
        bar_lds();   // prior compute's LDS reads done; vmcnt NOT drained
        // stage A tile from registers (compiler waits cur's vmcnt here)
        #pragma unroll
        for (int i = 0; i < 4; ++i) {
          int r = w * 16 + i * 4 + quad;
          ushortx4 u;
          u.x = f2bf(cur[i].x); u.y = f2bf(cur[i].y); u.z = f2bf(cur[i].z); u.w = f2bf(cur[i].w);
          *(ushortx4*)(&As[r * 72 + lm * 4]) = u;
        }
        // stage B tile (64 KB) async global->LDS: 8 gl_lds per thread
        #pragma unroll
        for (int c = 0; c < 8; ++c) {
          int kg = c & 1, ntl = (c >> 1) * 8 + w;
          const unsigned short* src = Wi_p + ((size_t)((kt * 2 + kg) * 32 + ntl) * 64 + lane) * 8;
          unsigned short* dst = &Bs[(size_t)((kg * 32 + ntl) * 64) * 8];
          gl_lds16(src, dst);
        }
        // vmcnt(4) below assumes the 8 gl_lds were ISSUED before the 4 A loads.
        __builtin_amdgcn_sched_barrier(0);
        if (kt < 7) {
          #pragma unroll
          for (int i = 0; i < 4; ++i)
            nxt[i] = *(const floatx4*)(xbase + (size_t)i * 1048576 + (kt + 1) * 64);
          asm volatile("s_waitcnt vmcnt(4) lgkmcnt(0)" ::: "memory");
        } else {
          asm volatile("s_waitcnt vmcnt(0) lgkmcnt(0)" ::: "memory");
        }
        __builtin_amdgcn_s_barrier();
        __builtin_amdgcn_sched_barrier(0);   // no ds_read may hoist above barrier
        #pragma unroll
        for (int ks = 0; ks < 2; ++ks) {
          short8 af[4];
          #pragma unroll
          for (int mt = 0; mt < 4; ++mt) {
            int m = wm * 64 + mt * 16 + lm;
            af[mt] = *(const short8*)(&As[m * 72 + ks * 32 + quad * 8]);
          }
          #pragma unroll
          for (int nt = 0; nt < 8; ++nt) {
            int g = nt >> 1, jc = nt & 1;
            int ntl = g * 8 + wn * 2 + jc;
            short8 bfv = *(const short8*)(&Bs[(size_t)((ks * 32 + ntl) * 64 + lane) * 8]);
            #pragma unroll
            for (int mt = 0; mt < 4; ++mt)
              acc[mt][nt] = __builtin_amdgcn_mfma_f32_16x16x32_bf16(af[mt], bfv, acc[mt][nt], 0, 0, 0);
          }
        }
        #pragma unroll
        for (int i = 0; i < 4; ++i) cur[i] = nxt[i];
      }
      // epilogue: per-cell 4-gate 8B RELAXED/AGENT atomic stores (write-through;
      // L2 never holds dirty xg lines).
      #pragma unroll
      for (int mt = 0; mt < 4; ++mt) {
        int bbase = b0 + wm * 64 + mt * 16 + quad * 4;
        #pragma unroll
        for (int jc = 0; jc < 2; ++jc) {
          int wv = wn * 2 + jc;
          #pragma unroll
          for (int rr = 0; rr < 4; ++rr) {
            size_t cell = ((size_t)s * 64 + ((bbase + rr) >> 2)) * 512 + wv * 64 + rr * 16 + lm;
            float g0 = acc[mt][0 + jc][rr] + bs_[0][jc];
            float g1 = acc[mt][2 + jc][rr] + bs_[1][jc];
            float g2 = acc[mt][4 + jc][rr] + bs_[2][jc];
            float g3 = acc[mt][6 + jc][rr] + bs_[3][jc];
            unsigned long long v64 =
                (unsigned long long)((unsigned int)f2bf(g0) | ((unsigned int)f2bf(g1) << 16)) |
                ((unsigned long long)((unsigned int)f2bf(g2) | ((unsigned int)f2bf(g3) << 16)) << 32);
            __hip_atomic_store((unsigned long long*)xg5 + cell, v64,
                               __ATOMIC_RELAXED, __HIP_MEMORY_SCOPE_AGENT);
          }
        }
      }
      // publish: __syncthreads drains every thread's vmcnt (stores acked at the
      // coherence point); one release add per tile.
      __syncthreads();
      __builtin_amdgcn_sched_barrier(0);
      if (tid == 0)
        __hip_atomic_fetch_add(&flags[t >> 7], 1u, __ATOMIC_RELEASE, __HIP_MEMORY_SCOPE_AGENT);
    }
  } else {
    // =========================== CONSUMER ====================================
    const int bb = blockIdx.x - NPROD;

    for (int i = tid; i < 2 * HBUF; i += 512) hb[i] = 0;

    // Wh B-fragments: gate g -> ntg = g*8 + w  (cols g*128 + w*16 + lm)
    short8 bfr[4][4];
    #pragma unroll
    for (int kk = 0; kk < 4; ++kk)
      #pragma unroll
      for (int g = 0; g < 4; ++g)
        bfr[kk][g] = *(const short8*)(Wh_p + ((size_t)(kk * 32 + g * 8 + w) * 64 + lane) * 8);

    float cst = 0.f;   // cell state for (row quad, col w*16+lm)

    // xg: cell index within block = tid; per-s stride = 64*512 cells = 32768 u64
    const unsigned long long* xp = (const unsigned long long*)xg5 + ((size_t)bb * 512 + tid);
    float* gw = gbw + w * 320;

    auto at_load8 = [](const unsigned long long* p) -> uint2v {
      unsigned long long v = __hip_atomic_load(p, __ATOMIC_RELAXED, __HIP_MEMORY_SCOPE_AGENT);
      uint2v r; r.x = (unsigned int)v; r.y = (unsigned int)(v >> 32); return r;
    };

    __syncthreads();   // hb zeros visible

    uint2v xga, xgb;

    auto substep = [&](const int rp, uint2v& xcur, int spre) {
      uint2v xv = xcur;

      // A-frags FIRST (they head the dependency chain): 4x ds_read_b128,
      // m=lm (batch rows; rows 4-15 read zeros). 304B row stride -> 16B align.
      short8 af[4];
      #pragma unroll
      for (int kk = 0; kk < 4; ++kk)
        af[kk] = *(const short8*)(&hb[rp * HBUF + lm * HBS + kk * 32 + quad * 8]);

      // xg prefetch issued after the af reads (independent; in flight across
      // bar_lds -- vmcnt not drained by it).
      if (spre < 512)
        xcur = at_load8(xp + (size_t)spre * 32768);

      floatx4 acc[4];
      #pragma unroll
      for (int g = 0; g < 4; ++g) { acc[g].x = 0.f; acc[g].y = 0.f; acc[g].z = 0.f; acc[g].w = 0.f; }
      #pragma unroll
      for (int kk = 0; kk < 4; ++kk)
        #pragma unroll
        for (int g = 0; g < 4; ++g)
          acc[g] = __builtin_amdgcn_mfma_f32_16x16x32_bf16(af[kk], bfr[kk][g], acc[g], 0, 0, 0);

      // intra-wave transpose: quad0 (rows 0-3 of C) -> [lm][r] gate-vectors
      if (lane < 16) {
        #pragma unroll
        for (int r = 0; r < 4; ++r) {
          floatx4 t4;
          t4.x = acc[0][r]; t4.y = acc[1][r]; t4.z = acc[2][r]; t4.w = acc[3][r];
          *(floatx4*)(gw + lm * 20 + r * 4) = t4;
        }
      }
      asm volatile("s_waitcnt lgkmcnt(0)" ::: "memory");   // same-wave DS order
      __builtin_amdgcn_sched_barrier(0);                   // rule-18 fence
      floatx4 gv = *(const floatx4*)(gw + lm * 20 + quad * 4);

      // EW: 1 cell/lane
      float pre0 = gv.x + bf2f((unsigned short)(xv.x & 0xffffu));
      float pre1 = gv.y + bf2f((unsigned short)(xv.x >> 16));
      float pre2 = gv.z + bf2f((unsigned short)(xv.y & 0xffffu));
      float pre3 = gv.w + bf2f((unsigned short)(xv.y >> 16));
      float cc = sigf(pre1) * cst + sigf(pre0) * tanhf_(pre2);
      cst = cc;
      float hv = sigf(pre3) * tanhf_(cc);
      hb[(rp ^ 1) * HBUF + quad * HBS + w * 16 + lm] = f2bf(hv);
      bar_lds();   // h(s+1) visible to all; vmcnt NOT drained
    };

    for (int c = 0; c < 8; ++c) {
      // wave 0 polls with RELAXED loads (no cache-invalidate side effects).
      if (w == 0) {
        while (__hip_atomic_load(&flags[c], __ATOMIC_RELAXED, __HIP_MEMORY_SCOPE_AGENT) < 128u)
          __builtin_amdgcn_s_sleep(2);
      }
      bar_lds();
      // fresh (re)load of the first two steps of this chunk -- overwrites any
      // tail prefetch that crossed an unpublished boundary.
      xga = at_load8(xp + (size_t)(c * 64) * 32768);
      xgb = at_load8(xp + (size_t)(c * 64 + 1) * 32768);
      #pragma unroll 1
      for (int s2 = 0; s2 < 64; s2 += 2) {
        int s = c * 64 + s2;
        substep(0, xga, s + 2);
        substep(1, xgb, s + 3);
      }
    }

    // head: h_last in hb buf 0 (s=511 writes buf 0)
    if (tid < 8) {
      int rw = tid >> 1, co = tid & 1;
      float a = bd[co];
      for (int j2 = 0; j2 < 128; ++j2)
        a += bf2f(hb[rw * HBS + j2]) * Wd[j2 * 2 + co];
      out[(bb * 4 + rw) * 2 + co] = a;
    }
  }
}

extern "C" void kernel_launch(void* const* d_in, const int* in_sizes, int n_in,
                              void* d_out, int out_size, void* d_ws, size_t ws_size,
                              hipStream_t stream) {
  const float* x  = (const float*)d_in[0];
  const float* Wi = (const float*)d_in[1];
  const float* Wh = (const float*)d_in[2];
  const float* b  = (const float*)d_in[3];
  const float* Wd = (const float*)d_in[4];
  const float* bd = (const float*)d_in[5];
  float* out = (float*)d_out;

  unsigned short* Wi_p = (unsigned short*)d_ws;            // 512 KB
  unsigned short* Wh_p = Wi_p + 262144;                    // 128 KB
  unsigned int*   flags = (unsigned int*)(Wh_p + 65536);   // 512 B (8 used)
  unsigned int*   xg5  = flags + 128;                      // 134.2 MB

  pack_kernel<<<1280, 256, 0, stream>>>(Wi, Wh, Wi_p, Wh_p, flags);
  fused_kernel<<<256, 512, 0, stream>>>(x, Wi_p, b, xg5, Wh_p, Wd, bd, out, flags);
}